// Round 11
// baseline (294.978 us; speedup 1.0000x reference)
//
#include <hip/hip_runtime.h>

#define DEVI __device__ __forceinline__

typedef short bf16x8 __attribute__((ext_vector_type(8)));
typedef float f32x4 __attribute__((ext_vector_type(4)));
typedef unsigned short u16;
typedef unsigned int u32;

// Problem constants
static constexpr int Bn = 2, S = 2048, E = 1024, H = 16, D = 64;
static constexpr int Mrows = Bn * S;          // 4096
static constexpr int N_QKV = 3 * E;           // 3072

DEVI u16 f2b(float f) {
  union { float f; u32 u; } c; c.f = f;
  return (u16)((c.u + 0x7FFFu + ((c.u >> 16) & 1u)) >> 16);
}

DEVI bf16x8 ld8(const u16* p) {
  union { uint4 u; bf16x8 v; } c;
  c.u = *reinterpret_cast<const uint4*>(p);
  return c.v;
}

#define MFMA(a, b, c) __builtin_amdgcn_mfma_f32_16x16x32_bf16(a, b, c, 0, 0, 0)

// global -> LDS async copy, 16B per lane. LDS dest must be wave-uniform-base + lane*16.
#define G2L16(gptr, lptr) \
  __builtin_amdgcn_global_load_lds((const __attribute__((address_space(1))) void*)(gptr), \
                                   (__attribute__((address_space(3))) void*)(lptr), 16, 0, 0)

// ---------------- fp32 -> bf16 elementwise (x) ----------------
__global__ void conv_bf16(const float* __restrict__ in, u16* __restrict__ out, int n4) {
  int i = blockIdx.x * blockDim.x + threadIdx.x;
  if (i < n4) {
    float4 f = reinterpret_cast<const float4*>(in)[i];
    ushort4 u;
    u.x = f2b(f.x); u.y = f2b(f.y); u.z = f2b(f.z); u.w = f2b(f.w);
    reinterpret_cast<ushort4*>(out)[i] = u;
  }
}

// ---------------- fp32 [R][C] -> bf16 [C][R] transpose (weights) ----------------
__global__ void transpose_bf16(const float* __restrict__ in, u16* __restrict__ out, int R, int C) {
  __shared__ float t[32][33];
  int bx = blockIdx.x * 32;  // C
  int by = blockIdx.y * 32;  // R
  int tx = threadIdx.x, ty = threadIdx.y;
#pragma unroll
  for (int k = 0; k < 32; k += 8)
    t[ty + k][tx] = in[(size_t)(by + ty + k) * C + bx + tx];
  __syncthreads();
#pragma unroll
  for (int k = 0; k < 32; k += 8)
    out[(size_t)(bx + ty + k) * R + by + tx] = f2b(t[tx][ty + k]);
}

// ---------------- GEMM1: qkv = xb @ wabT^T, BK=64 XOR-swizzle + REGISTER-PREFETCH ---------
// Round-8's G2L16 version exposed a full L2 drain at every barrier (3 phase-locked
// blocks/CU drain together -> ~40% idle). Here tile i+1 is loaded into registers
// (coalesced uint4, 8/thread) WHILE tile i computes; the barrier then only waits on
// ds_write of already-arrived data. XOR swizzle keeps ds_read_b128 2-way-free.
__global__ __launch_bounds__(256) void gemm_qkv(const u16* __restrict__ A, const u16* __restrict__ BT,
                                                u16* __restrict__ Qb, u16* __restrict__ Kb,
                                                u16* __restrict__ VbT) {
  constexpr int K = 1024, BK = 64;
  __shared__ __align__(16) u16 As[128 * BK];   // 16 KB, swizzled rows of 8 16B-groups
  __shared__ __align__(16) u16 Bs[128 * BK];
  int tid = threadIdx.x;
  int w = tid >> 6, lane = tid & 63, quad = lane >> 4, l15 = lane & 15;
  int m0 = blockIdx.x * 128, n0 = blockIdx.y * 128;
  int mw = (w >> 1) * 64, nw = (w & 1) * 64;
  const u16* Ab = A + (size_t)m0 * K;
  const u16* Bb = BT + (size_t)n0 * K;

  // staging descriptors: thread covers L = j*256+tid -> row L>>3, 16B-group (L&7)^(row&7)
  size_t goff[4]; int loff[4];
#pragma unroll
  for (int j = 0; j < 4; j++) {
    int L = j * 256 + tid;
    int row = L >> 3, cg = (L & 7) ^ (row & 7);
    goff[j] = (size_t)row * K + cg * 8;
    loff[j] = L * 16;
  }
  uint4 ra[4], rb[4];
#pragma unroll
  for (int j = 0; j < 4; j++) {
    ra[j] = *reinterpret_cast<const uint4*>(Ab + goff[j]);
    rb[j] = *reinterpret_cast<const uint4*>(Bb + goff[j]);
  }
  f32x4 acc[4][4] = {};
  for (int k0 = 0; k0 < K; k0 += BK) {
    __syncthreads();                 // previous iteration's LDS readers done
#pragma unroll
    for (int j = 0; j < 4; j++) {
      *reinterpret_cast<uint4*>((char*)As + loff[j]) = ra[j];
      *reinterpret_cast<uint4*>((char*)Bs + loff[j]) = rb[j];
    }
    __syncthreads();                 // LDS writes visible
    int kn = (k0 + BK) & (K - 1);    // wrapped: last prefetch is redundant-but-valid
#pragma unroll
    for (int j = 0; j < 4; j++) {
      ra[j] = *reinterpret_cast<const uint4*>(Ab + goff[j] + kn);
      rb[j] = *reinterpret_cast<const uint4*>(Bb + goff[j] + kn);
    }
#pragma unroll
    for (int kk = 0; kk < 2; kk++) {
      int sg = ((kk << 2) | quad) ^ (l15 & 7);   // swizzled 16B-group for this lane
      bf16x8 a[4], b[4];
#pragma unroll
      for (int i = 0; i < 4; i++) a[i] = ld8(&As[(mw + i * 16 + l15) * BK + sg * 8]);
#pragma unroll
      for (int i = 0; i < 4; i++) b[i] = ld8(&Bs[(nw + i * 16 + l15) * BK + sg * 8]);
#pragma unroll
      for (int mb = 0; mb < 4; mb++)
#pragma unroll
        for (int nb = 0; nb < 4; nb++)
          acc[mb][nb] = MFMA(a[mb], b[nb], acc[mb][nb]);
    }
  }
#pragma unroll
  for (int mb = 0; mb < 4; mb++) {
    int m = m0 + mw + mb * 16 + quad * 4;      // rows m..m+3 (tiles never straddle batch)
    int b = m >> 11, s = m & 2047;
#pragma unroll
    for (int nb = 0; nb < 4; nb++) {
      int n = n0 + nw + nb * 16 + l15;
      int sec = n >> 10, e = n & 1023, h = e >> 6, d = e & 63;
      int bh = b * H + h;
      if (sec == 0) {
#pragma unroll
        for (int r = 0; r < 4; r++)
          Qb[((size_t)bh * S + s + r) * D + d] = f2b(acc[mb][nb][r] * 0.125f);
      } else if (sec == 1) {
#pragma unroll
        for (int r = 0; r < 4; r++)
          Kb[((size_t)bh * S + s + r) * D + d] = f2b(acc[mb][nb][r]);
      } else {
        ushort4 v;
        v.x = f2b(acc[mb][nb][0]); v.y = f2b(acc[mb][nb][1]);
        v.z = f2b(acc[mb][nb][2]); v.w = f2b(acc[mb][nb][3]);
        *reinterpret_cast<ushort4*>(VbT + ((size_t)bh * D + d) * S + s) = v;
      }
    }
  }
}

// ---------------- Flash attention: merged paired q-tiles, single staging loop (unchanged) --
__global__ __launch_bounds__(256, 3) void attn(const u16* __restrict__ Qb, const u16* __restrict__ Kb,
                                               const u16* __restrict__ VbT, u16* __restrict__ Yb) {
  __shared__ __align__(16) u16 Ks[128 * 64];    // swizzled: (row, cg) at row*64 + (cg^(row&7))*8
  __shared__ __align__(16) u16 Vs[64 * 128];    // swizzled: (d, cg) at d*128 + (cg^(d&15))*8
  __shared__ __align__(16) u32 Ps[4][16 * 68];  // per-wave P[q=16][k=128] bf16, row stride 68 u32
  int w = threadIdx.x >> 6, lane = threadIdx.x & 63, quad = lane >> 4, l15 = lane & 15;
  int bh = blockIdx.x & 31, p = blockIdx.x >> 5;   // p in [0,16)
  int b = bh >> 4, h = bh & 15;
  int qtA = 31 - p, qtB = p;
  int ncA = (qtA + 2) >> 1, ncB = (qtB + 2) >> 1;  // staged chunks needed per tile

  const u16* Kbh = Kb + (size_t)bh * S * D;
  const u16* Vbh = VbT + (size_t)bh * D * S;
  u32* myP = &Ps[w][0];
  const u16* myP16 = (const u16*)myP;
  int prow = l15 * 68 + quad * 2;    // u32 index for this lane's P writes

  int qbA = qtA * 64 + w * 16, qbB = qtB * 64 + w * 16;
  int kmaxA = qbA + 16, kmaxB = qbB + 16;
  const u16* QpA = Qb + ((size_t)bh * S + qbA + l15) * D + quad * 8;
  const u16* QpB = Qb + ((size_t)bh * S + qbB + l15) * D + quad * 8;
  bf16x8 bqA0 = ld8(QpA), bqA1 = ld8(QpA + 32);
  bf16x8 bqB0 = ld8(QpB), bqB1 = ld8(QpB + 32);

  float lA = 0.f, lB = 0.f;
  f32x4 oA[4] = {}, oB[4] = {};
  int kbase = 0;

  auto process = [&](int q_base, int kmaxW, bf16x8 bq0, bf16x8 bq1, f32x4* o, float& lpart) {
    // ---- QK^T + exp + pack into wave-private P ----
#pragma unroll
    for (int mb = 0; mb < 8; mb++) {
      int kb = kbase + mb * 16;
      u32 pa = 0, pb = 0;
      if (kb < kmaxW) {              // wave-uniform
        int row = mb * 16 + l15;
        bf16x8 ak0 = ld8(&Ks[row * 64 + ((quad ^ (row & 7)) * 8)]);
        bf16x8 ak1 = ld8(&Ks[row * 64 + (((quad + 4) ^ (row & 7)) * 8)]);
        f32x4 z = {};
        z = MFMA(ak0, bq0, z);
        z = MFMA(ak1, bq1, z);
        if (kb == q_base) {          // diagonal subtile: mask k > q
#pragma unroll
          for (int r = 0; r < 4; r++)
            if (quad * 4 + r > l15) z[r] = -1e30f;
        }
        float p0 = __expf(z[0]), p1 = __expf(z[1]);
        float p2 = __expf(z[2]), p3 = __expf(z[3]);
        lpart += (p0 + p1) + (p2 + p3);
        pa = (u32)f2b(p0) | ((u32)f2b(p1) << 16);
        pb = (u32)f2b(p2) | ((u32)f2b(p3) << 16);
      }
      uint2 pw; pw.x = pa; pw.y = pb;
      *reinterpret_cast<uint2*>(&myP[prow + mb * 8]) = pw;   // ds_write_b64
    }
    // ---- O^T += V^T · P^T per 32-key chunk ----
#pragma unroll
    for (int ch = 0; ch < 4; ch++) {
      if (kbase + ch * 32 < kmaxW) { // wave-uniform
        bf16x8 bp = ld8(myP16 + l15 * 136 + ch * 32 + quad * 8);
#pragma unroll
        for (int dd = 0; dd < 4; dd++) {
          int rv = dd * 16 + l15;
          bf16x8 av = ld8(&Vs[rv * 128 + (((ch * 4 + quad) ^ (rv & 15)) * 8)]);
          o[dd] = MFMA(av, bp, o[dd]);
        }
      }
    }
  };

  for (int c = 0; c < ncA; c++) {
    kbase = c * 128;
    __syncthreads();               // previous chunk's readers done
    // ---- cooperative staging: K tile (16KB) ----
    const u16* Kg = Kbh + (size_t)kbase * D;
#pragma unroll
    for (int j = 0; j < 4; j++) {
      int L = (w * 4 + j) * 64 + lane;
      int row = L >> 3, cg = (L & 7) ^ (row & 7);
      G2L16(Kg + (size_t)row * 64 + cg * 8, (char*)Ks + L * 16);
    }
    // ---- cooperative staging: V^T tile (16KB) ----
    const u16* Vg = Vbh + kbase;
#pragma unroll
    for (int j = 0; j < 4; j++) {
      int L = (w * 4 + j) * 64 + lane;
      int row = L >> 4, cg = (L & 15) ^ (row & 15);
      G2L16(Vg + (size_t)row * S + cg * 8, (char*)Vs + L * 16);
    }
    __syncthreads();               // staging visible (barrier drains vmcnt)

    process(qbA, kmaxA, bqA0, bqA1, oA, lA);
    if (c < ncB)                   // block-uniform
      process(qbB, kmaxB, bqB0, bqB1, oB, lB);
  }

  // ---- epilogues: each wave owns the full k-range of its 16 q-rows ----
  {
    float l = lA; l += __shfl_xor(l, 16); l += __shfl_xor(l, 32);
    float rinv = 1.0f / l;
    u16* Yp = Yb + ((size_t)b * S + qbA + l15) * E + h * 64 + quad * 4;
#pragma unroll
    for (int dd = 0; dd < 4; dd++) {
      ushort4 y;
      y.x = f2b(oA[dd][0] * rinv); y.y = f2b(oA[dd][1] * rinv);
      y.z = f2b(oA[dd][2] * rinv); y.w = f2b(oA[dd][3] * rinv);
      *reinterpret_cast<ushort4*>(Yp + dd * 16) = y;
    }
  }
  {
    float l = lB; l += __shfl_xor(l, 16); l += __shfl_xor(l, 32);
    float rinv = 1.0f / l;
    u16* Yp = Yb + ((size_t)b * S + qbB + l15) * E + h * 64 + quad * 4;
#pragma unroll
    for (int dd = 0; dd < 4; dd++) {
      ushort4 y;
      y.x = f2b(oB[dd][0] * rinv); y.y = f2b(oB[dd][1] * rinv);
      y.z = f2b(oB[dd][2] * rinv); y.w = f2b(oB[dd][3] * rinv);
      *reinterpret_cast<ushort4*>(Yp + dd * 16) = y;
    }
  }
}

// ---------------- GEMM2: out = Yb @ wpbT^T, BK=64 XOR-swizzle + register-prefetch ---------
__global__ __launch_bounds__(256) void gemm_proj(const u16* __restrict__ A, const u16* __restrict__ BT,
                                                 float* __restrict__ out) {
  constexpr int K = 1024, BK = 64;
  __shared__ __align__(16) u16 As[128 * BK];
  __shared__ __align__(16) u16 Bs[128 * BK];
  int tid = threadIdx.x;
  int w = tid >> 6, lane = tid & 63, quad = lane >> 4, l15 = lane & 15;
  int m0 = blockIdx.x * 128, n0 = blockIdx.y * 128;
  int mw = (w >> 1) * 64, nw = (w & 1) * 64;
  const u16* Ab = A + (size_t)m0 * K;
  const u16* Bb = BT + (size_t)n0 * K;
  size_t goff[4]; int loff[4];
#pragma unroll
  for (int j = 0; j < 4; j++) {
    int L = j * 256 + tid;
    int row = L >> 3, cg = (L & 7) ^ (row & 7);
    goff[j] = (size_t)row * K + cg * 8;
    loff[j] = L * 16;
  }
  uint4 ra[4], rb[4];
#pragma unroll
  for (int j = 0; j < 4; j++) {
    ra[j] = *reinterpret_cast<const uint4*>(Ab + goff[j]);
    rb[j] = *reinterpret_cast<const uint4*>(Bb + goff[j]);
  }
  f32x4 acc[4][4] = {};
  for (int k0 = 0; k0 < K; k0 += BK) {
    __syncthreads();
#pragma unroll
    for (int j = 0; j < 4; j++) {
      *reinterpret_cast<uint4*>((char*)As + loff[j]) = ra[j];
      *reinterpret_cast<uint4*>((char*)Bs + loff[j]) = rb[j];
    }
    __syncthreads();
    int kn = (k0 + BK) & (K - 1);
#pragma unroll
    for (int j = 0; j < 4; j++) {
      ra[j] = *reinterpret_cast<const uint4*>(Ab + goff[j] + kn);
      rb[j] = *reinterpret_cast<const uint4*>(Bb + goff[j] + kn);
    }
#pragma unroll
    for (int kk = 0; kk < 2; kk++) {
      int sg = ((kk << 2) | quad) ^ (l15 & 7);
      bf16x8 a[4], b[4];
#pragma unroll
      for (int i = 0; i < 4; i++) a[i] = ld8(&As[(mw + i * 16 + l15) * BK + sg * 8]);
#pragma unroll
      for (int i = 0; i < 4; i++) b[i] = ld8(&Bs[(nw + i * 16 + l15) * BK + sg * 8]);
#pragma unroll
      for (int mb = 0; mb < 4; mb++)
#pragma unroll
        for (int nb = 0; nb < 4; nb++)
          acc[mb][nb] = MFMA(a[mb], b[nb], acc[mb][nb]);
    }
  }
#pragma unroll
  for (int mb = 0; mb < 4; mb++) {
    int m = m0 + mw + mb * 16 + quad * 4;
#pragma unroll
    for (int nb = 0; nb < 4; nb++) {
      int n = n0 + nw + nb * 16 + l15;
#pragma unroll
      for (int r = 0; r < 4; r++)
        out[(size_t)(m + r) * E + n] = acc[mb][nb][r];
    }
  }
}

extern "C" void kernel_launch(void* const* d_in, const int* in_sizes, int n_in,
                              void* d_out, int out_size, void* d_ws, size_t ws_size,
                              hipStream_t stream) {
  const float* x = (const float*)d_in[0];
  const float* w_attn = (const float*)d_in[1];
  const float* w_proj = (const float*)d_in[2];
  float* out = (float*)d_out;
  char* ws = (char*)d_ws;

  // workspace layout (bytes)
  u16* xb   = (u16*)(ws);                      // 4096*1024*2 = 8 MB
  u16* wabT = (u16*)(ws + 8388608);            // 3072*1024*2 = 6 MB
  u16* wpbT = (u16*)(ws + 14680064);           // 1024*1024*2 = 2 MB
  u16* Qb   = (u16*)(ws + 16777216);           // 8 MB
  u16* Kb   = (u16*)(ws + 25165824);           // 8 MB
  u16* VbT  = (u16*)(ws + 33554432);           // 8 MB
  u16* Yb   = (u16*)(ws + 41943040);           // 8 MB   (total 48 MB)

  conv_bf16<<<4096, 256, 0, stream>>>(x, xb, Mrows * E / 4);
  transpose_bf16<<<dim3(N_QKV / 32, E / 32), dim3(32, 8), 0, stream>>>(w_attn, wabT, E, N_QKV);
  transpose_bf16<<<dim3(E / 32, E / 32), dim3(32, 8), 0, stream>>>(w_proj, wpbT, E, E);
  gemm_qkv<<<dim3(Mrows / 128, N_QKV / 128), 256, 0, stream>>>(xb, wabT, Qb, Kb, VbT);
  attn<<<Bn * H * (S / 128), 256, 0, stream>>>(Qb, Kb, VbT, Yb);
  gemm_proj<<<dim3(Mrows / 128, E / 128), 256, 0, stream>>>(Yb, wpbT, out);
}

// Round 12
// 195.008 us; speedup vs baseline: 1.5126x; 1.5126x over previous
//
#include <hip/hip_runtime.h>

#define DEVI __device__ __forceinline__

typedef short bf16x8 __attribute__((ext_vector_type(8)));
typedef float f32x4 __attribute__((ext_vector_type(4)));
typedef unsigned short u16;
typedef unsigned int u32;

// Problem constants
static constexpr int Bn = 2, S = 2048, E = 1024, H = 16, D = 64;
static constexpr int Mrows = Bn * S;          // 4096
static constexpr int N_QKV = 3 * E;           // 3072

DEVI u16 f2b(float f) {
  union { float f; u32 u; } c; c.f = f;
  return (u16)((c.u + 0x7FFFu + ((c.u >> 16) & 1u)) >> 16);
}

DEVI bf16x8 ld8(const u16* p) {
  union { uint4 u; bf16x8 v; } c;
  c.u = *reinterpret_cast<const uint4*>(p);
  return c.v;
}

#define MFMA(a, b, c) __builtin_amdgcn_mfma_f32_16x16x32_bf16(a, b, c, 0, 0, 0)

// global -> LDS async copy, 16B per lane. LDS dest must be wave-uniform-base + lane*16.
#define G2L16(gptr, lptr) \
  __builtin_amdgcn_global_load_lds((const __attribute__((address_space(1))) void*)(gptr), \
                                   (__attribute__((address_space(3))) void*)(lptr), 16, 0, 0)

// ---------------- fp32 -> bf16 elementwise (x) ----------------
__global__ void conv_bf16(const float* __restrict__ in, u16* __restrict__ out, int n4) {
  int i = blockIdx.x * blockDim.x + threadIdx.x;
  if (i < n4) {
    float4 f = reinterpret_cast<const float4*>(in)[i];
    ushort4 u;
    u.x = f2b(f.x); u.y = f2b(f.y); u.z = f2b(f.z); u.w = f2b(f.w);
    reinterpret_cast<ushort4*>(out)[i] = u;
  }
}

// ---------------- fp32 [R][C] -> bf16 [C][R] transpose (weights) ----------------
__global__ void transpose_bf16(const float* __restrict__ in, u16* __restrict__ out, int R, int C) {
  __shared__ float t[32][33];
  int bx = blockIdx.x * 32;  // C
  int by = blockIdx.y * 32;  // R
  int tx = threadIdx.x, ty = threadIdx.y;
#pragma unroll
  for (int k = 0; k < 32; k += 8)
    t[ty + k][tx] = in[(size_t)(by + ty + k) * C + bx + tx];
  __syncthreads();
#pragma unroll
  for (int k = 0; k < 32; k += 8)
    out[(size_t)(bx + ty + k) * R + by + tx] = f2b(t[tx][ty + k]);
}

// ---------------- GEMM1: qkv = xb @ wabT^T, BK=64 XOR-swizzle + G2L16 DOUBLE-BUFFER -------
// r8's single-buffer G2L16 exposed a full L2 drain at every barrier (phase-locked blocks
// drain together, ~50% idle). r11's register-prefetch spilled to scratch (WRITE_SIZE 8x).
// Here: one barrier per iteration; after it, G2L16s for tile i+1 are issued into the OTHER
// LDS buffer, then tile i computes -- the prefetch has the whole compute phase to land,
// so the next barrier's vmcnt drain is ~free. No VGPR cost. 64KB LDS -> 2 blocks/CU.
__global__ __launch_bounds__(256) void gemm_qkv(const u16* __restrict__ A, const u16* __restrict__ BT,
                                                u16* __restrict__ Qb, u16* __restrict__ Kb,
                                                u16* __restrict__ VbT) {
  constexpr int K = 1024, BK = 64, NIT = K / BK;
  __shared__ __align__(16) u16 As[2][128 * BK];   // 2 x 16 KB, swizzled rows of 8 16B-groups
  __shared__ __align__(16) u16 Bs[2][128 * BK];
  int tid = threadIdx.x;
  int w = tid >> 6, lane = tid & 63, quad = lane >> 4, l15 = lane & 15;
  int m0 = blockIdx.x * 128, n0 = blockIdx.y * 128;
  int mw = (w >> 1) * 64, nw = (w & 1) * 64;
  const u16* Ab = A + (size_t)m0 * K;
  const u16* Bb = BT + (size_t)n0 * K;
  // staging descriptors: thread covers L = j*256+tid -> row L>>3, 16B-group (L&7)^(row&7)
  size_t goff[4]; int loff[4];
#pragma unroll
  for (int j = 0; j < 4; j++) {
    int L = j * 256 + tid;
    int row = L >> 3, cg = (L & 7) ^ (row & 7);
    goff[j] = (size_t)row * K + cg * 8;
    loff[j] = L * 16;
  }
  // prologue: stage tile 0 into buffer 0
#pragma unroll
  for (int j = 0; j < 4; j++) G2L16(Ab + goff[j], (char*)As[0] + loff[j]);
#pragma unroll
  for (int j = 0; j < 4; j++) G2L16(Bb + goff[j], (char*)Bs[0] + loff[j]);

  f32x4 acc[4][4] = {};
  for (int it = 0; it < NIT; it++) {
    int cur = it & 1, nxt = cur ^ 1;
    __syncthreads();   // tile it's loads complete; prior readers of buf nxt done
    if (it + 1 < NIT) {
      size_t kn = (size_t)(it + 1) * BK;
#pragma unroll
      for (int j = 0; j < 4; j++) G2L16(Ab + goff[j] + kn, (char*)As[nxt] + loff[j]);
#pragma unroll
      for (int j = 0; j < 4; j++) G2L16(Bb + goff[j] + kn, (char*)Bs[nxt] + loff[j]);
    }
#pragma unroll
    for (int kk = 0; kk < 2; kk++) {
      int sg = ((kk << 2) | quad) ^ (l15 & 7);   // swizzled 16B-group for this lane
      bf16x8 a[4], b[4];
#pragma unroll
      for (int i = 0; i < 4; i++) a[i] = ld8(&As[cur][(mw + i * 16 + l15) * BK + sg * 8]);
#pragma unroll
      for (int i = 0; i < 4; i++) b[i] = ld8(&Bs[cur][(nw + i * 16 + l15) * BK + sg * 8]);
#pragma unroll
      for (int mb = 0; mb < 4; mb++)
#pragma unroll
        for (int nb = 0; nb < 4; nb++)
          acc[mb][nb] = MFMA(a[mb], b[nb], acc[mb][nb]);
    }
  }
#pragma unroll
  for (int mb = 0; mb < 4; mb++) {
    int m = m0 + mw + mb * 16 + quad * 4;      // rows m..m+3 (tiles never straddle batch)
    int b = m >> 11, s = m & 2047;
#pragma unroll
    for (int nb = 0; nb < 4; nb++) {
      int n = n0 + nw + nb * 16 + l15;
      int sec = n >> 10, e = n & 1023, h = e >> 6, d = e & 63;
      int bh = b * H + h;
      if (sec == 0) {
#pragma unroll
        for (int r = 0; r < 4; r++)
          Qb[((size_t)bh * S + s + r) * D + d] = f2b(acc[mb][nb][r] * 0.125f);
      } else if (sec == 1) {
#pragma unroll
        for (int r = 0; r < 4; r++)
          Kb[((size_t)bh * S + s + r) * D + d] = f2b(acc[mb][nb][r]);
      } else {
        ushort4 v;
        v.x = f2b(acc[mb][nb][0]); v.y = f2b(acc[mb][nb][1]);
        v.z = f2b(acc[mb][nb][2]); v.w = f2b(acc[mb][nb][3]);
        *reinterpret_cast<ushort4*>(VbT + ((size_t)bh * D + d) * S + s) = v;
      }
    }
  }
}

// ---------------- Flash attention: merged paired q-tiles, single staging loop (unchanged) --
__global__ __launch_bounds__(256, 3) void attn(const u16* __restrict__ Qb, const u16* __restrict__ Kb,
                                               const u16* __restrict__ VbT, u16* __restrict__ Yb) {
  __shared__ __align__(16) u16 Ks[128 * 64];    // swizzled: (row, cg) at row*64 + (cg^(row&7))*8
  __shared__ __align__(16) u16 Vs[64 * 128];    // swizzled: (d, cg) at d*128 + (cg^(d&15))*8
  __shared__ __align__(16) u32 Ps[4][16 * 68];  // per-wave P[q=16][k=128] bf16, row stride 68 u32
  int w = threadIdx.x >> 6, lane = threadIdx.x & 63, quad = lane >> 4, l15 = lane & 15;
  int bh = blockIdx.x & 31, p = blockIdx.x >> 5;   // p in [0,16)
  int b = bh >> 4, h = bh & 15;
  int qtA = 31 - p, qtB = p;
  int ncA = (qtA + 2) >> 1, ncB = (qtB + 2) >> 1;  // staged chunks needed per tile

  const u16* Kbh = Kb + (size_t)bh * S * D;
  const u16* Vbh = VbT + (size_t)bh * D * S;
  u32* myP = &Ps[w][0];
  const u16* myP16 = (const u16*)myP;
  int prow = l15 * 68 + quad * 2;    // u32 index for this lane's P writes

  int qbA = qtA * 64 + w * 16, qbB = qtB * 64 + w * 16;
  int kmaxA = qbA + 16, kmaxB = qbB + 16;
  const u16* QpA = Qb + ((size_t)bh * S + qbA + l15) * D + quad * 8;
  const u16* QpB = Qb + ((size_t)bh * S + qbB + l15) * D + quad * 8;
  bf16x8 bqA0 = ld8(QpA), bqA1 = ld8(QpA + 32);
  bf16x8 bqB0 = ld8(QpB), bqB1 = ld8(QpB + 32);

  float lA = 0.f, lB = 0.f;
  f32x4 oA[4] = {}, oB[4] = {};
  int kbase = 0;

  auto process = [&](int q_base, int kmaxW, bf16x8 bq0, bf16x8 bq1, f32x4* o, float& lpart) {
    // ---- QK^T + exp + pack into wave-private P ----
#pragma unroll
    for (int mb = 0; mb < 8; mb++) {
      int kb = kbase + mb * 16;
      u32 pa = 0, pb = 0;
      if (kb < kmaxW) {              // wave-uniform
        int row = mb * 16 + l15;
        bf16x8 ak0 = ld8(&Ks[row * 64 + ((quad ^ (row & 7)) * 8)]);
        bf16x8 ak1 = ld8(&Ks[row * 64 + (((quad + 4) ^ (row & 7)) * 8)]);
        f32x4 z = {};
        z = MFMA(ak0, bq0, z);
        z = MFMA(ak1, bq1, z);
        if (kb == q_base) {          // diagonal subtile: mask k > q
#pragma unroll
          for (int r = 0; r < 4; r++)
            if (quad * 4 + r > l15) z[r] = -1e30f;
        }
        float p0 = __expf(z[0]), p1 = __expf(z[1]);
        float p2 = __expf(z[2]), p3 = __expf(z[3]);
        lpart += (p0 + p1) + (p2 + p3);
        pa = (u32)f2b(p0) | ((u32)f2b(p1) << 16);
        pb = (u32)f2b(p2) | ((u32)f2b(p3) << 16);
      }
      uint2 pw; pw.x = pa; pw.y = pb;
      *reinterpret_cast<uint2*>(&myP[prow + mb * 8]) = pw;   // ds_write_b64
    }
    // ---- O^T += V^T · P^T per 32-key chunk ----
#pragma unroll
    for (int ch = 0; ch < 4; ch++) {
      if (kbase + ch * 32 < kmaxW) { // wave-uniform
        bf16x8 bp = ld8(myP16 + l15 * 136 + ch * 32 + quad * 8);
#pragma unroll
        for (int dd = 0; dd < 4; dd++) {
          int rv = dd * 16 + l15;
          bf16x8 av = ld8(&Vs[rv * 128 + (((ch * 4 + quad) ^ (rv & 15)) * 8)]);
          o[dd] = MFMA(av, bp, o[dd]);
        }
      }
    }
  };

  for (int c = 0; c < ncA; c++) {
    kbase = c * 128;
    __syncthreads();               // previous chunk's readers done
    // ---- cooperative staging: K tile (16KB) ----
    const u16* Kg = Kbh + (size_t)kbase * D;
#pragma unroll
    for (int j = 0; j < 4; j++) {
      int L = (w * 4 + j) * 64 + lane;
      int row = L >> 3, cg = (L & 7) ^ (row & 7);
      G2L16(Kg + (size_t)row * 64 + cg * 8, (char*)Ks + L * 16);
    }
    // ---- cooperative staging: V^T tile (16KB) ----
    const u16* Vg = Vbh + kbase;
#pragma unroll
    for (int j = 0; j < 4; j++) {
      int L = (w * 4 + j) * 64 + lane;
      int row = L >> 4, cg = (L & 15) ^ (row & 15);
      G2L16(Vg + (size_t)row * S + cg * 8, (char*)Vs + L * 16);
    }
    __syncthreads();               // staging visible (barrier drains vmcnt)

    process(qbA, kmaxA, bqA0, bqA1, oA, lA);
    if (c < ncB)                   // block-uniform
      process(qbB, kmaxB, bqB0, bqB1, oB, lB);
  }

  // ---- epilogues: each wave owns the full k-range of its 16 q-rows ----
  {
    float l = lA; l += __shfl_xor(l, 16); l += __shfl_xor(l, 32);
    float rinv = 1.0f / l;
    u16* Yp = Yb + ((size_t)b * S + qbA + l15) * E + h * 64 + quad * 4;
#pragma unroll
    for (int dd = 0; dd < 4; dd++) {
      ushort4 y;
      y.x = f2b(oA[dd][0] * rinv); y.y = f2b(oA[dd][1] * rinv);
      y.z = f2b(oA[dd][2] * rinv); y.w = f2b(oA[dd][3] * rinv);
      *reinterpret_cast<ushort4*>(Yp + dd * 16) = y;
    }
  }
  {
    float l = lB; l += __shfl_xor(l, 16); l += __shfl_xor(l, 32);
    float rinv = 1.0f / l;
    u16* Yp = Yb + ((size_t)b * S + qbB + l15) * E + h * 64 + quad * 4;
#pragma unroll
    for (int dd = 0; dd < 4; dd++) {
      ushort4 y;
      y.x = f2b(oB[dd][0] * rinv); y.y = f2b(oB[dd][1] * rinv);
      y.z = f2b(oB[dd][2] * rinv); y.w = f2b(oB[dd][3] * rinv);
      *reinterpret_cast<ushort4*>(Yp + dd * 16) = y;
    }
  }
}

// ---------------- GEMM2: out = Yb @ wpbT^T, BK=64 XOR-swizzle + G2L16 double-buffer ------
// 256 blocks = 1/CU: no cross-block overlap exists, so intra-block async prefetch is
// the only latency cover available here.
__global__ __launch_bounds__(256) void gemm_proj(const u16* __restrict__ A, const u16* __restrict__ BT,
                                                 float* __restrict__ out) {
  constexpr int K = 1024, BK = 64, NIT = K / BK;
  __shared__ __align__(16) u16 As[2][128 * BK];
  __shared__ __align__(16) u16 Bs[2][128 * BK];
  int tid = threadIdx.x;
  int w = tid >> 6, lane = tid & 63, quad = lane >> 4, l15 = lane & 15;
  int m0 = blockIdx.x * 128, n0 = blockIdx.y * 128;
  int mw = (w >> 1) * 64, nw = (w & 1) * 64;
  const u16* Ab = A + (size_t)m0 * K;
  const u16* Bb = BT + (size_t)n0 * K;
  size_t goff[4]; int loff[4];
#pragma unroll
  for (int j = 0; j < 4; j++) {
    int L = j * 256 + tid;
    int row = L >> 3, cg = (L & 7) ^ (row & 7);
    goff[j] = (size_t)row * K + cg * 8;
    loff[j] = L * 16;
  }
#pragma unroll
  for (int j = 0; j < 4; j++) G2L16(Ab + goff[j], (char*)As[0] + loff[j]);
#pragma unroll
  for (int j = 0; j < 4; j++) G2L16(Bb + goff[j], (char*)Bs[0] + loff[j]);

  f32x4 acc[4][4] = {};
  for (int it = 0; it < NIT; it++) {
    int cur = it & 1, nxt = cur ^ 1;
    __syncthreads();
    if (it + 1 < NIT) {
      size_t kn = (size_t)(it + 1) * BK;
#pragma unroll
      for (int j = 0; j < 4; j++) G2L16(Ab + goff[j] + kn, (char*)As[nxt] + loff[j]);
#pragma unroll
      for (int j = 0; j < 4; j++) G2L16(Bb + goff[j] + kn, (char*)Bs[nxt] + loff[j]);
    }
#pragma unroll
    for (int kk = 0; kk < 2; kk++) {
      int sg = ((kk << 2) | quad) ^ (l15 & 7);
      bf16x8 a[4], b[4];
#pragma unroll
      for (int i = 0; i < 4; i++) a[i] = ld8(&As[cur][(mw + i * 16 + l15) * BK + sg * 8]);
#pragma unroll
      for (int i = 0; i < 4; i++) b[i] = ld8(&Bs[cur][(nw + i * 16 + l15) * BK + sg * 8]);
#pragma unroll
      for (int mb = 0; mb < 4; mb++)
#pragma unroll
        for (int nb = 0; nb < 4; nb++)
          acc[mb][nb] = MFMA(a[mb], b[nb], acc[mb][nb]);
    }
  }
#pragma unroll
  for (int mb = 0; mb < 4; mb++) {
    int m = m0 + mw + mb * 16 + quad * 4;
#pragma unroll
    for (int nb = 0; nb < 4; nb++) {
      int n = n0 + nw + nb * 16 + l15;
#pragma unroll
      for (int r = 0; r < 4; r++)
        out[(size_t)(m + r) * E + n] = acc[mb][nb][r];
    }
  }
}

extern "C" void kernel_launch(void* const* d_in, const int* in_sizes, int n_in,
                              void* d_out, int out_size, void* d_ws, size_t ws_size,
                              hipStream_t stream) {
  const float* x = (const float*)d_in[0];
  const float* w_attn = (const float*)d_in[1];
  const float* w_proj = (const float*)d_in[2];
  float* out = (float*)d_out;
  char* ws = (char*)d_ws;

  // workspace layout (bytes)
  u16* xb   = (u16*)(ws);                      // 4096*1024*2 = 8 MB
  u16* wabT = (u16*)(ws + 8388608);            // 3072*1024*2 = 6 MB
  u16* wpbT = (u16*)(ws + 14680064);           // 1024*1024*2 = 2 MB
  u16* Qb   = (u16*)(ws + 16777216);           // 8 MB
  u16* Kb   = (u16*)(ws + 25165824);           // 8 MB
  u16* VbT  = (u16*)(ws + 33554432);           // 8 MB
  u16* Yb   = (u16*)(ws + 41943040);           // 8 MB   (total 48 MB)

  conv_bf16<<<4096, 256, 0, stream>>>(x, xb, Mrows * E / 4);
  transpose_bf16<<<dim3(N_QKV / 32, E / 32), dim3(32, 8), 0, stream>>>(w_attn, wabT, E, N_QKV);
  transpose_bf16<<<dim3(E / 32, E / 32), dim3(32, 8), 0, stream>>>(w_proj, wpbT, E, E);
  gemm_qkv<<<dim3(Mrows / 128, N_QKV / 128), 256, 0, stream>>>(xb, wabT, Qb, Kb, VbT);
  attn<<<Bn * H * (S / 128), 256, 0, stream>>>(Qb, Kb, VbT, Yb);
  gemm_proj<<<dim3(Mrows / 128, E / 128), 256, 0, stream>>>(Yb, wpbT, out);
}

// Round 13
// 185.004 us; speedup vs baseline: 1.5944x; 1.0541x over previous
//
#include <hip/hip_runtime.h>

#define DEVI __device__ __forceinline__

typedef short bf16x8 __attribute__((ext_vector_type(8)));
typedef float f32x4 __attribute__((ext_vector_type(4)));
typedef unsigned short u16;
typedef unsigned int u32;

// Problem constants
static constexpr int Bn = 2, S = 2048, E = 1024, H = 16, D = 64;
static constexpr int Mrows = Bn * S;          // 4096
static constexpr int N_QKV = 3 * E;           // 3072

DEVI u16 f2b(float f) {
  union { float f; u32 u; } c; c.f = f;
  return (u16)((c.u + 0x7FFFu + ((c.u >> 16) & 1u)) >> 16);
}

DEVI bf16x8 ld8(const u16* p) {
  union { uint4 u; bf16x8 v; } c;
  c.u = *reinterpret_cast<const uint4*>(p);
  return c.v;
}

#define MFMA(a, b, c) __builtin_amdgcn_mfma_f32_16x16x32_bf16(a, b, c, 0, 0, 0)

// global -> LDS async copy, 16B per lane. LDS dest must be wave-uniform-base + lane*16.
#define G2L16(gptr, lptr) \
  __builtin_amdgcn_global_load_lds((const __attribute__((address_space(1))) void*)(gptr), \
                                   (__attribute__((address_space(3))) void*)(lptr), 16, 0, 0)

// ---------------- Fused prep: x->bf16, w_attn^T->bf16, w_proj^T->bf16 (ONE launch) --------
// Sections by blockIdx.x: [0,4096) conv x (float4/thread); [4096,7168) transpose w_attn
// (1024x3072 -> 3072x1024); [7168,8192) transpose w_proj (1024x1024 -> 1024x1024).
// Fusing 3 launches into 1 removes ~2 inter-kernel gaps (~10us each, serial stream).
__global__ __launch_bounds__(256) void prep(const float* __restrict__ x,
                                            const float* __restrict__ w_attn,
                                            const float* __restrict__ w_proj,
                                            u16* __restrict__ xb, u16* __restrict__ wabT,
                                            u16* __restrict__ wpbT) {
  __shared__ float t[32][33];
  int blk = blockIdx.x, tid = threadIdx.x;
  if (blk < 4096) {
    int i = blk * 256 + tid;                   // n4 = 4096*1024/4 = 1048576
    float4 f = reinterpret_cast<const float4*>(x)[i];
    ushort4 u;
    u.x = f2b(f.x); u.y = f2b(f.y); u.z = f2b(f.z); u.w = f2b(f.w);
    reinterpret_cast<ushort4*>(xb)[i] = u;
    return;
  }
  const float* in; u16* out; int R, C, bx, by;
  if (blk < 7168) {
    int q = blk - 4096;                        // 96 x 32 tiles
    in = w_attn; out = wabT; R = E; C = N_QKV;
    bx = (q % 96) * 32; by = (q / 96) * 32;
  } else {
    int q = blk - 7168;                        // 32 x 32 tiles
    in = w_proj; out = wpbT; R = E; C = E;
    bx = (q % 32) * 32; by = (q / 32) * 32;
  }
  int tx = tid & 31, ty = tid >> 5;            // 32 x 8
#pragma unroll
  for (int k = 0; k < 32; k += 8)
    t[ty + k][tx] = in[(size_t)(by + ty + k) * C + bx + tx];
  __syncthreads();
#pragma unroll
  for (int k = 0; k < 32; k += 8)
    out[(size_t)(bx + ty + k) * R + by + tx] = f2b(t[tx][ty + k]);
}

// ---------------- GEMM1: qkv = xb @ wabT^T, BK=64 + XOR-swizzled LDS (r8 measured-best) ---
// Single-buffer G2L16 staging. Pipelining attempts (r5/r9/r11/r12 per-wave prefetch,
// reg-prefetch, LDS dbuf) all regressed -- this structure's plateau, per m97/m131-141.
__global__ __launch_bounds__(256) void gemm_qkv(const u16* __restrict__ A, const u16* __restrict__ BT,
                                                u16* __restrict__ Qb, u16* __restrict__ Kb,
                                                u16* __restrict__ VbT) {
  constexpr int K = 1024, BK = 64;
  __shared__ __align__(16) u16 As[128 * BK];   // 16 KB, swizzled rows of 8 16B-groups
  __shared__ __align__(16) u16 Bs[128 * BK];
  int tid = threadIdx.x;
  int w = tid >> 6, lane = tid & 63, quad = lane >> 4, l15 = lane & 15;
  int m0 = blockIdx.x * 128, n0 = blockIdx.y * 128;
  int mw = (w >> 1) * 64, nw = (w & 1) * 64;
  const u16* Ab = A + (size_t)m0 * K;
  const u16* Bb = BT + (size_t)n0 * K;
  f32x4 acc[4][4] = {};
  for (int k0 = 0; k0 < K; k0 += BK) {
#pragma unroll
    for (int j = 0; j < 4; j++) {
      int L = j * 256 + tid;
      int row = L >> 3, cg = (L & 7) ^ (row & 7);
      G2L16(Ab + (size_t)row * K + k0 + cg * 8, (char*)As + L * 16);
    }
#pragma unroll
    for (int j = 0; j < 4; j++) {
      int L = j * 256 + tid;
      int row = L >> 3, cg = (L & 7) ^ (row & 7);
      G2L16(Bb + (size_t)row * K + k0 + cg * 8, (char*)Bs + L * 16);
    }
    __syncthreads();
#pragma unroll
    for (int kk = 0; kk < 2; kk++) {
      int sg = ((kk << 2) | quad) ^ (l15 & 7);   // swizzled 16B-group for this lane
      bf16x8 a[4], b[4];
#pragma unroll
      for (int i = 0; i < 4; i++) a[i] = ld8(&As[(mw + i * 16 + l15) * BK + sg * 8]);
#pragma unroll
      for (int i = 0; i < 4; i++) b[i] = ld8(&Bs[(nw + i * 16 + l15) * BK + sg * 8]);
#pragma unroll
      for (int mb = 0; mb < 4; mb++)
#pragma unroll
        for (int nb = 0; nb < 4; nb++)
          acc[mb][nb] = MFMA(a[mb], b[nb], acc[mb][nb]);
    }
    __syncthreads();
  }
#pragma unroll
  for (int mb = 0; mb < 4; mb++) {
    int m = m0 + mw + mb * 16 + quad * 4;      // rows m..m+3 (tiles never straddle batch)
    int b = m >> 11, s = m & 2047;
#pragma unroll
    for (int nb = 0; nb < 4; nb++) {
      int n = n0 + nw + nb * 16 + l15;
      int sec = n >> 10, e = n & 1023, h = e >> 6, d = e & 63;
      int bh = b * H + h;
      if (sec == 0) {
#pragma unroll
        for (int r = 0; r < 4; r++)
          Qb[((size_t)bh * S + s + r) * D + d] = f2b(acc[mb][nb][r] * 0.125f);
      } else if (sec == 1) {
#pragma unroll
        for (int r = 0; r < 4; r++)
          Kb[((size_t)bh * S + s + r) * D + d] = f2b(acc[mb][nb][r]);
      } else {
        ushort4 v;
        v.x = f2b(acc[mb][nb][0]); v.y = f2b(acc[mb][nb][1]);
        v.z = f2b(acc[mb][nb][2]); v.w = f2b(acc[mb][nb][3]);
        *reinterpret_cast<ushort4*>(VbT + ((size_t)bh * D + d) * S + s) = v;
      }
    }
  }
}

// ---------------- Flash attention: merged paired q-tiles, single staging loop (r9) --------
__global__ __launch_bounds__(256, 3) void attn(const u16* __restrict__ Qb, const u16* __restrict__ Kb,
                                               const u16* __restrict__ VbT, u16* __restrict__ Yb) {
  __shared__ __align__(16) u16 Ks[128 * 64];    // swizzled: (row, cg) at row*64 + (cg^(row&7))*8
  __shared__ __align__(16) u16 Vs[64 * 128];    // swizzled: (d, cg) at d*128 + (cg^(d&15))*8
  __shared__ __align__(16) u32 Ps[4][16 * 68];  // per-wave P[q=16][k=128] bf16, row stride 68 u32
  int w = threadIdx.x >> 6, lane = threadIdx.x & 63, quad = lane >> 4, l15 = lane & 15;
  int bh = blockIdx.x & 31, p = blockIdx.x >> 5;   // p in [0,16)
  int b = bh >> 4, h = bh & 15;
  int qtA = 31 - p, qtB = p;
  int ncA = (qtA + 2) >> 1, ncB = (qtB + 2) >> 1;  // staged chunks needed per tile

  const u16* Kbh = Kb + (size_t)bh * S * D;
  const u16* Vbh = VbT + (size_t)bh * D * S;
  u32* myP = &Ps[w][0];
  const u16* myP16 = (const u16*)myP;
  int prow = l15 * 68 + quad * 2;    // u32 index for this lane's P writes

  int qbA = qtA * 64 + w * 16, qbB = qtB * 64 + w * 16;
  int kmaxA = qbA + 16, kmaxB = qbB + 16;
  const u16* QpA = Qb + ((size_t)bh * S + qbA + l15) * D + quad * 8;
  const u16* QpB = Qb + ((size_t)bh * S + qbB + l15) * D + quad * 8;
  bf16x8 bqA0 = ld8(QpA), bqA1 = ld8(QpA + 32);
  bf16x8 bqB0 = ld8(QpB), bqB1 = ld8(QpB + 32);

  float lA = 0.f, lB = 0.f;
  f32x4 oA[4] = {}, oB[4] = {};
  int kbase = 0;

  auto process = [&](int q_base, int kmaxW, bf16x8 bq0, bf16x8 bq1, f32x4* o, float& lpart) {
    // ---- QK^T + exp + pack into wave-private P ----
#pragma unroll
    for (int mb = 0; mb < 8; mb++) {
      int kb = kbase + mb * 16;
      u32 pa = 0, pb = 0;
      if (kb < kmaxW) {              // wave-uniform
        int row = mb * 16 + l15;
        bf16x8 ak0 = ld8(&Ks[row * 64 + ((quad ^ (row & 7)) * 8)]);
        bf16x8 ak1 = ld8(&Ks[row * 64 + (((quad + 4) ^ (row & 7)) * 8)]);
        f32x4 z = {};
        z = MFMA(ak0, bq0, z);
        z = MFMA(ak1, bq1, z);
        if (kb == q_base) {          // diagonal subtile: mask k > q
#pragma unroll
          for (int r = 0; r < 4; r++)
            if (quad * 4 + r > l15) z[r] = -1e30f;
        }
        float p0 = __expf(z[0]), p1 = __expf(z[1]);
        float p2 = __expf(z[2]), p3 = __expf(z[3]);
        lpart += (p0 + p1) + (p2 + p3);
        pa = (u32)f2b(p0) | ((u32)f2b(p1) << 16);
        pb = (u32)f2b(p2) | ((u32)f2b(p3) << 16);
      }
      uint2 pw; pw.x = pa; pw.y = pb;
      *reinterpret_cast<uint2*>(&myP[prow + mb * 8]) = pw;   // ds_write_b64
    }
    // ---- O^T += V^T · P^T per 32-key chunk ----
#pragma unroll
    for (int ch = 0; ch < 4; ch++) {
      if (kbase + ch * 32 < kmaxW) { // wave-uniform
        bf16x8 bp = ld8(myP16 + l15 * 136 + ch * 32 + quad * 8);
#pragma unroll
        for (int dd = 0; dd < 4; dd++) {
          int rv = dd * 16 + l15;
          bf16x8 av = ld8(&Vs[rv * 128 + (((ch * 4 + quad) ^ (rv & 15)) * 8)]);
          o[dd] = MFMA(av, bp, o[dd]);
        }
      }
    }
  };

  for (int c = 0; c < ncA; c++) {
    kbase = c * 128;
    __syncthreads();               // previous chunk's readers done
    // ---- cooperative staging: K tile (16KB) ----
    const u16* Kg = Kbh + (size_t)kbase * D;
#pragma unroll
    for (int j = 0; j < 4; j++) {
      int L = (w * 4 + j) * 64 + lane;
      int row = L >> 3, cg = (L & 7) ^ (row & 7);
      G2L16(Kg + (size_t)row * 64 + cg * 8, (char*)Ks + L * 16);
    }
    // ---- cooperative staging: V^T tile (16KB) ----
    const u16* Vg = Vbh + kbase;
#pragma unroll
    for (int j = 0; j < 4; j++) {
      int L = (w * 4 + j) * 64 + lane;
      int row = L >> 4, cg = (L & 15) ^ (row & 15);
      G2L16(Vg + (size_t)row * S + cg * 8, (char*)Vs + L * 16);
    }
    __syncthreads();               // staging visible (barrier drains vmcnt)

    process(qbA, kmaxA, bqA0, bqA1, oA, lA);
    if (c < ncB)                   // block-uniform
      process(qbB, kmaxB, bqB0, bqB1, oB, lB);
  }

  // ---- epilogues: each wave owns the full k-range of its 16 q-rows ----
  {
    float l = lA; l += __shfl_xor(l, 16); l += __shfl_xor(l, 32);
    float rinv = 1.0f / l;
    u16* Yp = Yb + ((size_t)b * S + qbA + l15) * E + h * 64 + quad * 4;
#pragma unroll
    for (int dd = 0; dd < 4; dd++) {
      ushort4 y;
      y.x = f2b(oA[dd][0] * rinv); y.y = f2b(oA[dd][1] * rinv);
      y.z = f2b(oA[dd][2] * rinv); y.w = f2b(oA[dd][3] * rinv);
      *reinterpret_cast<ushort4*>(Yp + dd * 16) = y;
    }
  }
  {
    float l = lB; l += __shfl_xor(l, 16); l += __shfl_xor(l, 32);
    float rinv = 1.0f / l;
    u16* Yp = Yb + ((size_t)b * S + qbB + l15) * E + h * 64 + quad * 4;
#pragma unroll
    for (int dd = 0; dd < 4; dd++) {
      ushort4 y;
      y.x = f2b(oB[dd][0] * rinv); y.y = f2b(oB[dd][1] * rinv);
      y.z = f2b(oB[dd][2] * rinv); y.w = f2b(oB[dd][3] * rinv);
      *reinterpret_cast<ushort4*>(Yp + dd * 16) = y;
    }
  }
}

// ---------------- GEMM2: out = Yb @ wpbT^T, BK=64 + XOR swizzle, fp32 out (r8) ------------
__global__ __launch_bounds__(256) void gemm_proj(const u16* __restrict__ A, const u16* __restrict__ BT,
                                                 float* __restrict__ out) {
  constexpr int K = 1024, BK = 64;
  __shared__ __align__(16) u16 As[128 * BK];
  __shared__ __align__(16) u16 Bs[128 * BK];
  int tid = threadIdx.x;
  int w = tid >> 6, lane = tid & 63, quad = lane >> 4, l15 = lane & 15;
  int m0 = blockIdx.x * 128, n0 = blockIdx.y * 128;
  int mw = (w >> 1) * 64, nw = (w & 1) * 64;
  const u16* Ab = A + (size_t)m0 * K;
  const u16* Bb = BT + (size_t)n0 * K;
  f32x4 acc[4][4] = {};
  for (int k0 = 0; k0 < K; k0 += BK) {
#pragma unroll
    for (int j = 0; j < 4; j++) {
      int L = j * 256 + tid;
      int row = L >> 3, cg = (L & 7) ^ (row & 7);
      G2L16(Ab + (size_t)row * K + k0 + cg * 8, (char*)As + L * 16);
    }
#pragma unroll
    for (int j = 0; j < 4; j++) {
      int L = j * 256 + tid;
      int row = L >> 3, cg = (L & 7) ^ (row & 7);
      G2L16(Bb + (size_t)row * K + k0 + cg * 8, (char*)Bs + L * 16);
    }
    __syncthreads();
#pragma unroll
    for (int kk = 0; kk < 2; kk++) {
      int sg = ((kk << 2) | quad) ^ (l15 & 7);
      bf16x8 a[4], b[4];
#pragma unroll
      for (int i = 0; i < 4; i++) a[i] = ld8(&As[(mw + i * 16 + l15) * BK + sg * 8]);
#pragma unroll
      for (int i = 0; i < 4; i++) b[i] = ld8(&Bs[(nw + i * 16 + l15) * BK + sg * 8]);
#pragma unroll
      for (int mb = 0; mb < 4; mb++)
#pragma unroll
        for (int nb = 0; nb < 4; nb++)
          acc[mb][nb] = MFMA(a[mb], b[nb], acc[mb][nb]);
    }
    __syncthreads();
  }
#pragma unroll
  for (int mb = 0; mb < 4; mb++) {
    int m = m0 + mw + mb * 16 + quad * 4;
#pragma unroll
    for (int nb = 0; nb < 4; nb++) {
      int n = n0 + nw + nb * 16 + l15;
#pragma unroll
      for (int r = 0; r < 4; r++)
        out[(size_t)(m + r) * E + n] = acc[mb][nb][r];
    }
  }
}

extern "C" void kernel_launch(void* const* d_in, const int* in_sizes, int n_in,
                              void* d_out, int out_size, void* d_ws, size_t ws_size,
                              hipStream_t stream) {
  const float* x = (const float*)d_in[0];
  const float* w_attn = (const float*)d_in[1];
  const float* w_proj = (const float*)d_in[2];
  float* out = (float*)d_out;
  char* ws = (char*)d_ws;

  // workspace layout (bytes)
  u16* xb   = (u16*)(ws);                      // 4096*1024*2 = 8 MB
  u16* wabT = (u16*)(ws + 8388608);            // 3072*1024*2 = 6 MB
  u16* wpbT = (u16*)(ws + 14680064);           // 1024*1024*2 = 2 MB
  u16* Qb   = (u16*)(ws + 16777216);           // 8 MB
  u16* Kb   = (u16*)(ws + 25165824);           // 8 MB
  u16* VbT  = (u16*)(ws + 33554432);           // 8 MB
  u16* Yb   = (u16*)(ws + 41943040);           // 8 MB   (total 48 MB)

  prep<<<8192, 256, 0, stream>>>(x, w_attn, w_proj, xb, wabT, wpbT);
  gemm_qkv<<<dim3(Mrows / 128, N_QKV / 128), 256, 0, stream>>>(xb, wabT, Qb, Kb, VbT);
  attn<<<Bn * H * (S / 128), 256, 0, stream>>>(Qb, Kb, VbT, Yb);
  gemm_proj<<<dim3(Mrows / 128, E / 128), 256, 0, stream>>>(Yb, wpbT, out);
}

// Round 14
// 171.470 us; speedup vs baseline: 1.7203x; 1.0789x over previous
//
#include <hip/hip_runtime.h>

#define DEVI __device__ __forceinline__

typedef short bf16x8 __attribute__((ext_vector_type(8)));
typedef float f32x4 __attribute__((ext_vector_type(4)));
typedef unsigned short u16;
typedef unsigned int u32;

// Problem constants
static constexpr int Bn = 2, S = 2048, E = 1024, H = 16, D = 64;
static constexpr int Mrows = Bn * S;          // 4096
static constexpr int N_QKV = 3 * E;           // 3072

DEVI u16 f2b(float f) {
  union { float f; u32 u; } c; c.f = f;
  return (u16)((c.u + 0x7FFFu + ((c.u >> 16) & 1u)) >> 16);
}

DEVI bf16x8 ld8(const u16* p) {
  union { uint4 u; bf16x8 v; } c;
  c.u = *reinterpret_cast<const uint4*>(p);
  return c.v;
}

#define MFMA(a, b, c) __builtin_amdgcn_mfma_f32_16x16x32_bf16(a, b, c, 0, 0, 0)

// global -> LDS async copy, 16B per lane. LDS dest must be wave-uniform-base + lane*16.
#define G2L16(gptr, lptr) \
  __builtin_amdgcn_global_load_lds((const __attribute__((address_space(1))) void*)(gptr), \
                                   (__attribute__((address_space(3))) void*)(lptr), 16, 0, 0)

// ---------------- Fused prep: transposes FIRST, conv LAST ----------------
// r13 ran conv first / transposes last; wabT's scattered writes were still draining in
// L2 when gemm_qkv read them (+12us on gemm_qkv). Order restored to match r8's separate-
// kernel sequence: [0,3072) w_attn^T, [3072,4096) w_proj^T, [4096,8192) conv x.
__global__ __launch_bounds__(256) void prep(const float* __restrict__ x,
                                            const float* __restrict__ w_attn,
                                            const float* __restrict__ w_proj,
                                            u16* __restrict__ xb, u16* __restrict__ wabT,
                                            u16* __restrict__ wpbT) {
  __shared__ float t[32][33];
  int blk = blockIdx.x, tid = threadIdx.x;
  if (blk >= 4096) {
    int i = (blk - 4096) * 256 + tid;          // n4 = 4096*1024/4 = 1048576
    float4 f = reinterpret_cast<const float4*>(x)[i];
    ushort4 u;
    u.x = f2b(f.x); u.y = f2b(f.y); u.z = f2b(f.z); u.w = f2b(f.w);
    reinterpret_cast<ushort4*>(xb)[i] = u;
    return;
  }
  const float* in; u16* out; int R, C, bx, by;
  if (blk < 3072) {
    in = w_attn; out = wabT; R = E; C = N_QKV;  // 96 x 32 tiles
    bx = (blk % 96) * 32; by = (blk / 96) * 32;
  } else {
    int q = blk - 3072;                         // 32 x 32 tiles
    in = w_proj; out = wpbT; R = E; C = E;
    bx = (q % 32) * 32; by = (q / 32) * 32;
  }
  int tx = tid & 31, ty = tid >> 5;             // 32 x 8
#pragma unroll
  for (int k = 0; k < 32; k += 8)
    t[ty + k][tx] = in[(size_t)(by + ty + k) * C + bx + tx];
  __syncthreads();
#pragma unroll
  for (int k = 0; k < 32; k += 8)
    out[(size_t)(bx + ty + k) * R + by + tx] = f2b(t[tx][ty + k]);
}

// ---------------- GEMM1: qkv = xb @ wabT^T, 128x64 tile, BK=64, XOR swizzle ----------------
// Half-width tiles double the grid (1536 blocks = 6/CU): co-resident blocks with
// independent cadence fill each other's barrier drains (the r8 convoy idle). Intra-block
// pipelining is 0-for-4 (r5/r9/r11/r12) -- cross-block overlap is the remaining lever.
__global__ __launch_bounds__(256) void gemm_qkv(const u16* __restrict__ A, const u16* __restrict__ BT,
                                                u16* __restrict__ Qb, u16* __restrict__ Kb,
                                                u16* __restrict__ VbT) {
  constexpr int K = 1024, BK = 64;
  __shared__ __align__(16) u16 As[128 * BK];   // 16 KB, swizzled rows of 8 16B-groups
  __shared__ __align__(16) u16 Bs[64 * BK];    // 8 KB
  int tid = threadIdx.x;
  int w = tid >> 6, lane = tid & 63, quad = lane >> 4, l15 = lane & 15;
  int m0 = blockIdx.x * 128, n0 = blockIdx.y * 64;
  int mw = (w >> 1) * 64, nw = (w & 1) * 32;   // wave-tile 64x32
  const u16* Ab = A + (size_t)m0 * K;
  const u16* Bb = BT + (size_t)n0 * K;
  f32x4 acc[4][2] = {};
  for (int k0 = 0; k0 < K; k0 += BK) {
#pragma unroll
    for (int j = 0; j < 4; j++) {
      int L = j * 256 + tid;
      int row = L >> 3, cg = (L & 7) ^ (row & 7);
      G2L16(Ab + (size_t)row * K + k0 + cg * 8, (char*)As + L * 16);
    }
#pragma unroll
    for (int j = 0; j < 2; j++) {
      int L = j * 256 + tid;
      int row = L >> 3, cg = (L & 7) ^ (row & 7);
      G2L16(Bb + (size_t)row * K + k0 + cg * 8, (char*)Bs + L * 16);
    }
    __syncthreads();
#pragma unroll
    for (int kk = 0; kk < 2; kk++) {
      int sg = ((kk << 2) | quad) ^ (l15 & 7);   // swizzled 16B-group for this lane
      bf16x8 a[4], b[2];
#pragma unroll
      for (int i = 0; i < 4; i++) a[i] = ld8(&As[(mw + i * 16 + l15) * BK + sg * 8]);
#pragma unroll
      for (int i = 0; i < 2; i++) b[i] = ld8(&Bs[(nw + i * 16 + l15) * BK + sg * 8]);
#pragma unroll
      for (int mb = 0; mb < 4; mb++)
#pragma unroll
        for (int nb = 0; nb < 2; nb++)
          acc[mb][nb] = MFMA(a[mb], b[nb], acc[mb][nb]);
    }
    __syncthreads();
  }
#pragma unroll
  for (int mb = 0; mb < 4; mb++) {
    int m = m0 + mw + mb * 16 + quad * 4;      // rows m..m+3 (tiles never straddle batch)
    int b = m >> 11, s = m & 2047;
#pragma unroll
    for (int nb = 0; nb < 2; nb++) {
      int n = n0 + nw + nb * 16 + l15;
      int sec = n >> 10, e = n & 1023, h = e >> 6, d = e & 63;
      int bh = b * H + h;
      if (sec == 0) {
#pragma unroll
        for (int r = 0; r < 4; r++)
          Qb[((size_t)bh * S + s + r) * D + d] = f2b(acc[mb][nb][r] * 0.125f);
      } else if (sec == 1) {
#pragma unroll
        for (int r = 0; r < 4; r++)
          Kb[((size_t)bh * S + s + r) * D + d] = f2b(acc[mb][nb][r]);
      } else {
        ushort4 v;
        v.x = f2b(acc[mb][nb][0]); v.y = f2b(acc[mb][nb][1]);
        v.z = f2b(acc[mb][nb][2]); v.w = f2b(acc[mb][nb][3]);
        *reinterpret_cast<ushort4*>(VbT + ((size_t)bh * D + d) * S + s) = v;
      }
    }
  }
}

// ---------------- Flash attention: merged paired q-tiles, single staging loop (r9) --------
__global__ __launch_bounds__(256, 3) void attn(const u16* __restrict__ Qb, const u16* __restrict__ Kb,
                                               const u16* __restrict__ VbT, u16* __restrict__ Yb) {
  __shared__ __align__(16) u16 Ks[128 * 64];    // swizzled: (row, cg) at row*64 + (cg^(row&7))*8
  __shared__ __align__(16) u16 Vs[64 * 128];    // swizzled: (d, cg) at d*128 + (cg^(d&15))*8
  __shared__ __align__(16) u32 Ps[4][16 * 68];  // per-wave P[q=16][k=128] bf16, row stride 68 u32
  int w = threadIdx.x >> 6, lane = threadIdx.x & 63, quad = lane >> 4, l15 = lane & 15;
  int bh = blockIdx.x & 31, p = blockIdx.x >> 5;   // p in [0,16)
  int b = bh >> 4, h = bh & 15;
  int qtA = 31 - p, qtB = p;
  int ncA = (qtA + 2) >> 1, ncB = (qtB + 2) >> 1;  // staged chunks needed per tile

  const u16* Kbh = Kb + (size_t)bh * S * D;
  const u16* Vbh = VbT + (size_t)bh * D * S;
  u32* myP = &Ps[w][0];
  const u16* myP16 = (const u16*)myP;
  int prow = l15 * 68 + quad * 2;    // u32 index for this lane's P writes

  int qbA = qtA * 64 + w * 16, qbB = qtB * 64 + w * 16;
  int kmaxA = qbA + 16, kmaxB = qbB + 16;
  const u16* QpA = Qb + ((size_t)bh * S + qbA + l15) * D + quad * 8;
  const u16* QpB = Qb + ((size_t)bh * S + qbB + l15) * D + quad * 8;
  bf16x8 bqA0 = ld8(QpA), bqA1 = ld8(QpA + 32);
  bf16x8 bqB0 = ld8(QpB), bqB1 = ld8(QpB + 32);

  float lA = 0.f, lB = 0.f;
  f32x4 oA[4] = {}, oB[4] = {};
  int kbase = 0;

  auto process = [&](int q_base, int kmaxW, bf16x8 bq0, bf16x8 bq1, f32x4* o, float& lpart) {
    // ---- QK^T + exp + pack into wave-private P ----
#pragma unroll
    for (int mb = 0; mb < 8; mb++) {
      int kb = kbase + mb * 16;
      u32 pa = 0, pb = 0;
      if (kb < kmaxW) {              // wave-uniform
        int row = mb * 16 + l15;
        bf16x8 ak0 = ld8(&Ks[row * 64 + ((quad ^ (row & 7)) * 8)]);
        bf16x8 ak1 = ld8(&Ks[row * 64 + (((quad + 4) ^ (row & 7)) * 8)]);
        f32x4 z = {};
        z = MFMA(ak0, bq0, z);
        z = MFMA(ak1, bq1, z);
        if (kb == q_base) {          // diagonal subtile: mask k > q
#pragma unroll
          for (int r = 0; r < 4; r++)
            if (quad * 4 + r > l15) z[r] = -1e30f;
        }
        float p0 = __expf(z[0]), p1 = __expf(z[1]);
        float p2 = __expf(z[2]), p3 = __expf(z[3]);
        lpart += (p0 + p1) + (p2 + p3);
        pa = (u32)f2b(p0) | ((u32)f2b(p1) << 16);
        pb = (u32)f2b(p2) | ((u32)f2b(p3) << 16);
      }
      uint2 pw; pw.x = pa; pw.y = pb;
      *reinterpret_cast<uint2*>(&myP[prow + mb * 8]) = pw;   // ds_write_b64
    }
    // ---- O^T += V^T · P^T per 32-key chunk ----
#pragma unroll
    for (int ch = 0; ch < 4; ch++) {
      if (kbase + ch * 32 < kmaxW) { // wave-uniform
        bf16x8 bp = ld8(myP16 + l15 * 136 + ch * 32 + quad * 8);
#pragma unroll
        for (int dd = 0; dd < 4; dd++) {
          int rv = dd * 16 + l15;
          bf16x8 av = ld8(&Vs[rv * 128 + (((ch * 4 + quad) ^ (rv & 15)) * 8)]);
          o[dd] = MFMA(av, bp, o[dd]);
        }
      }
    }
  };

  for (int c = 0; c < ncA; c++) {
    kbase = c * 128;
    __syncthreads();               // previous chunk's readers done
    // ---- cooperative staging: K tile (16KB) ----
    const u16* Kg = Kbh + (size_t)kbase * D;
#pragma unroll
    for (int j = 0; j < 4; j++) {
      int L = (w * 4 + j) * 64 + lane;
      int row = L >> 3, cg = (L & 7) ^ (row & 7);
      G2L16(Kg + (size_t)row * 64 + cg * 8, (char*)Ks + L * 16);
    }
    // ---- cooperative staging: V^T tile (16KB) ----
    const u16* Vg = Vbh + kbase;
#pragma unroll
    for (int j = 0; j < 4; j++) {
      int L = (w * 4 + j) * 64 + lane;
      int row = L >> 4, cg = (L & 15) ^ (row & 15);
      G2L16(Vg + (size_t)row * S + cg * 8, (char*)Vs + L * 16);
    }
    __syncthreads();               // staging visible (barrier drains vmcnt)

    process(qbA, kmaxA, bqA0, bqA1, oA, lA);
    if (c < ncB)                   // block-uniform
      process(qbB, kmaxB, bqB0, bqB1, oB, lB);
  }

  // ---- epilogues: each wave owns the full k-range of its 16 q-rows ----
  {
    float l = lA; l += __shfl_xor(l, 16); l += __shfl_xor(l, 32);
    float rinv = 1.0f / l;
    u16* Yp = Yb + ((size_t)b * S + qbA + l15) * E + h * 64 + quad * 4;
#pragma unroll
    for (int dd = 0; dd < 4; dd++) {
      ushort4 y;
      y.x = f2b(oA[dd][0] * rinv); y.y = f2b(oA[dd][1] * rinv);
      y.z = f2b(oA[dd][2] * rinv); y.w = f2b(oA[dd][3] * rinv);
      *reinterpret_cast<ushort4*>(Yp + dd * 16) = y;
    }
  }
  {
    float l = lB; l += __shfl_xor(l, 16); l += __shfl_xor(l, 32);
    float rinv = 1.0f / l;
    u16* Yp = Yb + ((size_t)b * S + qbB + l15) * E + h * 64 + quad * 4;
#pragma unroll
    for (int dd = 0; dd < 4; dd++) {
      ushort4 y;
      y.x = f2b(oB[dd][0] * rinv); y.y = f2b(oB[dd][1] * rinv);
      y.z = f2b(oB[dd][2] * rinv); y.w = f2b(oB[dd][3] * rinv);
      *reinterpret_cast<ushort4*>(Yp + dd * 16) = y;
    }
  }
}

// ---------------- GEMM2: out = Yb @ wpbT^T, 128x64 tile (512 blocks = 2/CU), fp32 out ----
__global__ __launch_bounds__(256) void gemm_proj(const u16* __restrict__ A, const u16* __restrict__ BT,
                                                 float* __restrict__ out) {
  constexpr int K = 1024, BK = 64;
  __shared__ __align__(16) u16 As[128 * BK];   // 16 KB
  __shared__ __align__(16) u16 Bs[64 * BK];    // 8 KB
  int tid = threadIdx.x;
  int w = tid >> 6, lane = tid & 63, quad = lane >> 4, l15 = lane & 15;
  int m0 = blockIdx.x * 128, n0 = blockIdx.y * 64;
  int mw = (w >> 1) * 64, nw = (w & 1) * 32;
  const u16* Ab = A + (size_t)m0 * K;
  const u16* Bb = BT + (size_t)n0 * K;
  f32x4 acc[4][2] = {};
  for (int k0 = 0; k0 < K; k0 += BK) {
#pragma unroll
    for (int j = 0; j < 4; j++) {
      int L = j * 256 + tid;
      int row = L >> 3, cg = (L & 7) ^ (row & 7);
      G2L16(Ab + (size_t)row * K + k0 + cg * 8, (char*)As + L * 16);
    }
#pragma unroll
    for (int j = 0; j < 2; j++) {
      int L = j * 256 + tid;
      int row = L >> 3, cg = (L & 7) ^ (row & 7);
      G2L16(Bb + (size_t)row * K + k0 + cg * 8, (char*)Bs + L * 16);
    }
    __syncthreads();
#pragma unroll
    for (int kk = 0; kk < 2; kk++) {
      int sg = ((kk << 2) | quad) ^ (l15 & 7);
      bf16x8 a[4], b[2];
#pragma unroll
      for (int i = 0; i < 4; i++) a[i] = ld8(&As[(mw + i * 16 + l15) * BK + sg * 8]);
#pragma unroll
      for (int i = 0; i < 2; i++) b[i] = ld8(&Bs[(nw + i * 16 + l15) * BK + sg * 8]);
#pragma unroll
      for (int mb = 0; mb < 4; mb++)
#pragma unroll
        for (int nb = 0; nb < 2; nb++)
          acc[mb][nb] = MFMA(a[mb], b[nb], acc[mb][nb]);
    }
    __syncthreads();
  }
#pragma unroll
  for (int mb = 0; mb < 4; mb++) {
    int m = m0 + mw + mb * 16 + quad * 4;
#pragma unroll
    for (int nb = 0; nb < 2; nb++) {
      int n = n0 + nw + nb * 16 + l15;
#pragma unroll
      for (int r = 0; r < 4; r++)
        out[(size_t)(m + r) * E + n] = acc[mb][nb][r];
    }
  }
}

extern "C" void kernel_launch(void* const* d_in, const int* in_sizes, int n_in,
                              void* d_out, int out_size, void* d_ws, size_t ws_size,
                              hipStream_t stream) {
  const float* x = (const float*)d_in[0];
  const float* w_attn = (const float*)d_in[1];
  const float* w_proj = (const float*)d_in[2];
  float* out = (float*)d_out;
  char* ws = (char*)d_ws;

  // workspace layout (bytes)
  u16* xb   = (u16*)(ws);                      // 4096*1024*2 = 8 MB
  u16* wabT = (u16*)(ws + 8388608);            // 3072*1024*2 = 6 MB
  u16* wpbT = (u16*)(ws + 14680064);           // 1024*1024*2 = 2 MB
  u16* Qb   = (u16*)(ws + 16777216);           // 8 MB
  u16* Kb   = (u16*)(ws + 25165824);           // 8 MB
  u16* VbT  = (u16*)(ws + 33554432);           // 8 MB
  u16* Yb   = (u16*)(ws + 41943040);           // 8 MB   (total 48 MB)

  prep<<<8192, 256, 0, stream>>>(x, w_attn, w_proj, xb, wabT, wpbT);
  gemm_qkv<<<dim3(Mrows / 128, N_QKV / 64), 256, 0, stream>>>(xb, wabT, Qb, Kb, VbT);
  attn<<<Bn * H * (S / 128), 256, 0, stream>>>(Qb, Kb, VbT, Yb);
  gemm_proj<<<dim3(Mrows / 128, E / 64), 256, 0, stream>>>(Yb, wpbT, out);
}